// Round 2
// baseline (1140.880 us; speedup 1.0000x reference)
//
#include <hip/hip_runtime.h>

#define N_NODES 200000
#define F_IN 128
#define HID 16

// ---------------- Stage 1: h = x @ W1  ([N,128] @ [128,16]) ----------------
__global__ __launch_bounds__(256) void gemm1_kernel(const float* __restrict__ x,
                                                    const float* __restrict__ W1,
                                                    float* __restrict__ h) {
    __shared__ float w[F_IN * HID];  // 8 KB
    int tid = threadIdx.x;
    for (int i = tid; i < F_IN * HID; i += 256) w[i] = W1[i];
    __syncthreads();

    int row = blockIdx.x * 256 + tid;
    if (row >= N_NODES) return;

    float acc[HID];
#pragma unroll
    for (int j = 0; j < HID; j++) acc[j] = 0.f;

    const float4* xr = reinterpret_cast<const float4*>(x + (size_t)row * F_IN);
#pragma unroll 4
    for (int k4 = 0; k4 < F_IN / 4; k4++) {
        float4 xv = xr[k4];
        const float* wr = &w[k4 * 4 * HID];
#pragma unroll
        for (int j = 0; j < HID; j++) acc[j] += xv.x * wr[j];
#pragma unroll
        for (int j = 0; j < HID; j++) acc[j] += xv.y * wr[HID + j];
#pragma unroll
        for (int j = 0; j < HID; j++) acc[j] += xv.z * wr[2 * HID + j];
#pragma unroll
        for (int j = 0; j < HID; j++) acc[j] += xv.w * wr[3 * HID + j];
    }

    float4* hr = reinterpret_cast<float4*>(h + (size_t)row * HID);
#pragma unroll
    for (int q = 0; q < HID / 4; q++)
        hr[q] = make_float4(acc[4 * q], acc[4 * q + 1], acc[4 * q + 2], acc[4 * q + 3]);
}

// ======================= CSR build (per call, reused by both layers) =======

__global__ __launch_bounds__(256) void count_kernel(const int* __restrict__ dst,
                                                    int* __restrict__ deg, int n_edges) {
    int e = blockIdx.x * 256 + threadIdx.x;
    if (e < n_edges) atomicAdd(&deg[dst[e]], 1);
}

// Per-block exclusive scan of deg -> offsets, block totals -> blockSums
__global__ __launch_bounds__(256) void scan1_kernel(const int* __restrict__ deg,
                                                    int* __restrict__ offsets,
                                                    int* __restrict__ blockSums) {
    __shared__ int s[256];
    int i = blockIdx.x * 256 + threadIdx.x;
    int t = threadIdx.x;
    int v0 = (i < N_NODES) ? deg[i] : 0;
    s[t] = v0;
    __syncthreads();
    for (int off = 1; off < 256; off <<= 1) {
        int v = (t >= off) ? s[t - off] : 0;
        __syncthreads();
        s[t] += v;
        __syncthreads();
    }
    if (i < N_NODES) offsets[i] = s[t] - v0;  // exclusive
    if (t == 255) blockSums[blockIdx.x] = s[255];
}

// Scan the (<=1024) block sums in a single block
__global__ __launch_bounds__(1024) void scan2_kernel(int* __restrict__ blockSums, int nb) {
    __shared__ int s[1024];
    int t = threadIdx.x;
    s[t] = (t < nb) ? blockSums[t] : 0;
    __syncthreads();
    for (int off = 1; off < 1024; off <<= 1) {
        int v = (t >= off) ? s[t - off] : 0;
        __syncthreads();
        s[t] += v;
        __syncthreads();
    }
    if (t < nb) blockSums[t] = (t == 0) ? 0 : s[t - 1];  // exclusive
}

__global__ __launch_bounds__(256) void scan3_kernel(int* __restrict__ offsets,
                                                    int* __restrict__ cursor,
                                                    const int* __restrict__ blockSums,
                                                    int n_edges) {
    int i = blockIdx.x * 256 + threadIdx.x;
    if (i < N_NODES) {
        int v = offsets[i] + blockSums[blockIdx.x];
        offsets[i] = v;
        cursor[i] = v;
    }
    if (i == 0) offsets[N_NODES] = n_edges;
}

__global__ __launch_bounds__(256) void fill_kernel(const int* __restrict__ src,
                                                   const int* __restrict__ dst,
                                                   const float* __restrict__ ew,
                                                   int* __restrict__ cursor,
                                                   int2* __restrict__ entries, int n_edges) {
    int e = blockIdx.x * 256 + threadIdx.x;
    if (e >= n_edges) return;
    int pos = atomicAdd(&cursor[dst[e]], 1);
    entries[pos] = make_int2(src[e], __float_as_int(ew[e]));
}

// ============ Layer-1 aggregation fused with relu(.+b1) @ W2 ===============
// 16 lanes per node (lane = output feature). 256 threads = 16 nodes/block.
__global__ __launch_bounds__(256) void agg_mid_kernel(const float* __restrict__ h,
                                                      const int* __restrict__ offsets,
                                                      const int2* __restrict__ entries,
                                                      const float* __restrict__ b1,
                                                      const float* __restrict__ W2,
                                                      float* __restrict__ h2) {
    __shared__ float w2[HID * HID];
    __shared__ float bs[HID];
    int t = threadIdx.x;
    if (t < HID * HID) w2[t] = W2[t];
    if (t < HID) bs[t] = b1[t];
    __syncthreads();

    int node = blockIdx.x * 16 + (t >> 4);
    int lane = t & 15;
    if (node >= N_NODES) return;

    int beg = offsets[node];
    int end = offsets[node + 1];
    float acc = 0.f;
    for (int p = beg; p < end; ++p) {
        int2 e = entries[p];
        acc += h[(size_t)e.x * HID + lane] * __int_as_float(e.y);
    }
    float hv = fmaxf(acc + bs[lane], 0.f);

    // h2[node][lane] = sum_k hv_k * W2[k][lane]  via intra-wave shuffle
    int gbase = (t & 63) & ~15;
    float acc2 = 0.f;
#pragma unroll
    for (int k = 0; k < HID; k++) {
        float hk = __shfl(hv, gbase + k, 64);
        acc2 += hk * w2[k * HID + lane];
    }
    h2[(size_t)node * HID + lane] = acc2;
}

// ============ Layer-2 aggregation fused with relu(.+b2)·Wd + bd ============
__global__ __launch_bounds__(256) void agg_final_kernel(const float* __restrict__ h2,
                                                        const int* __restrict__ offsets,
                                                        const int2* __restrict__ entries,
                                                        const float* __restrict__ b2,
                                                        const float* __restrict__ Wd,
                                                        const float* __restrict__ bd,
                                                        float* __restrict__ out) {
    __shared__ float wd[HID];
    __shared__ float bs[HID];
    __shared__ float bdv;
    int t = threadIdx.x;
    if (t < HID) { wd[t] = Wd[t]; bs[t] = b2[t]; }
    if (t == 0) bdv = bd[0];
    __syncthreads();

    int node = blockIdx.x * 16 + (t >> 4);
    int lane = t & 15;
    if (node >= N_NODES) return;

    int beg = offsets[node];
    int end = offsets[node + 1];
    float acc = 0.f;
    for (int p = beg; p < end; ++p) {
        int2 e = entries[p];
        acc += h2[(size_t)e.x * HID + lane] * __int_as_float(e.y);
    }
    float v = fmaxf(acc + bs[lane], 0.f) * wd[lane];
#pragma unroll
    for (int off = 8; off; off >>= 1) v += __shfl_xor(v, off, 64);
    if (lane == 0) out[node] = v + bdv;
}

// =================== Fallback path (R1): atomic scatter ====================
__global__ __launch_bounds__(256) void scatter_kernel(const float* __restrict__ h,
                                                      const int* __restrict__ src,
                                                      const int* __restrict__ dst,
                                                      const float* __restrict__ ew,
                                                      float* __restrict__ agg,
                                                      int n_edges) {
    long long idx = (long long)blockIdx.x * 256 + threadIdx.x;
    long long total = (long long)n_edges * HID;
    if (idx >= total) return;
    int e = (int)(idx >> 4);
    int j = (int)(idx & (HID - 1));
    float val = h[(size_t)src[e] * HID + j] * ew[e];
    atomicAdd(&agg[(size_t)dst[e] * HID + j], val);
}

__global__ __launch_bounds__(256) void gemm2_kernel(const float* __restrict__ agg,
                                                    const float* __restrict__ b1,
                                                    const float* __restrict__ W2,
                                                    float* __restrict__ h2) {
    __shared__ float w[HID * HID];
    __shared__ float bias[HID];
    int tid = threadIdx.x;
    if (tid < HID * HID) w[tid] = W2[tid];
    if (tid < HID) bias[tid] = b1[tid];
    __syncthreads();
    int row = blockIdx.x * 256 + tid;
    if (row >= N_NODES) return;
    float hv[HID];
    const float4* ar = reinterpret_cast<const float4*>(agg + (size_t)row * HID);
#pragma unroll
    for (int q = 0; q < 4; q++) {
        float4 v = ar[q];
        hv[4 * q + 0] = fmaxf(v.x + bias[4 * q + 0], 0.f);
        hv[4 * q + 1] = fmaxf(v.y + bias[4 * q + 1], 0.f);
        hv[4 * q + 2] = fmaxf(v.z + bias[4 * q + 2], 0.f);
        hv[4 * q + 3] = fmaxf(v.w + bias[4 * q + 3], 0.f);
    }
    float acc[HID];
#pragma unroll
    for (int j = 0; j < HID; j++) acc[j] = 0.f;
#pragma unroll
    for (int k = 0; k < HID; k++) {
        float hk = hv[k];
#pragma unroll
        for (int j = 0; j < HID; j++) acc[j] += hk * w[k * HID + j];
    }
    float4* hr = reinterpret_cast<float4*>(h2 + (size_t)row * HID);
#pragma unroll
    for (int q = 0; q < 4; q++)
        hr[q] = make_float4(acc[4 * q], acc[4 * q + 1], acc[4 * q + 2], acc[4 * q + 3]);
}

__global__ __launch_bounds__(256) void final_kernel(const float* __restrict__ agg,
                                                    const float* __restrict__ b2,
                                                    const float* __restrict__ Wd,
                                                    const float* __restrict__ bd,
                                                    float* __restrict__ out) {
    __shared__ float wd[HID];
    __shared__ float bias[HID];
    __shared__ float bdv;
    int tid = threadIdx.x;
    if (tid < HID) { wd[tid] = Wd[tid]; bias[tid] = b2[tid]; }
    if (tid == 0) bdv = bd[0];
    __syncthreads();
    int row = blockIdx.x * 256 + tid;
    if (row >= N_NODES) return;
    const float4* ar = reinterpret_cast<const float4*>(agg + (size_t)row * HID);
    float acc = bdv;
#pragma unroll
    for (int q = 0; q < 4; q++) {
        float4 v = ar[q];
        acc += fmaxf(v.x + bias[4 * q + 0], 0.f) * wd[4 * q + 0];
        acc += fmaxf(v.y + bias[4 * q + 1], 0.f) * wd[4 * q + 1];
        acc += fmaxf(v.z + bias[4 * q + 2], 0.f) * wd[4 * q + 2];
        acc += fmaxf(v.w + bias[4 * q + 3], 0.f) * wd[4 * q + 3];
    }
    out[row] = acc;
}

extern "C" void kernel_launch(void* const* d_in, const int* in_sizes, int n_in,
                              void* d_out, int out_size, void* d_ws, size_t ws_size,
                              hipStream_t stream) {
    const float* x    = (const float*)d_in[0];
    const int*   esrc = (const int*)d_in[1];
    const int*   edst = (const int*)d_in[2];
    const float* ew   = (const float*)d_in[3];
    const float* W1   = (const float*)d_in[4];
    const float* b1   = (const float*)d_in[5];
    const float* W2   = (const float*)d_in[6];
    const float* b2   = (const float*)d_in[7];
    const float* Wd   = (const float*)d_in[8];
    const float* bd   = (const float*)d_in[9];
    float* out = (float*)d_out;

    int n_edges = in_sizes[1];

    // ---- workspace layout (16B-aligned sections) ----
    size_t node_buf = (size_t)N_NODES * HID * sizeof(float);        // 12,800,000
    size_t off_bytes = (((size_t)(N_NODES + 1) * 4 + 15) / 16) * 16; // 800,016
    size_t cur_bytes = (size_t)N_NODES * 4;                          // 800,000
    int num_node_blocks = (N_NODES + 255) / 256;                     // 782
    size_t bsum_bytes = (((size_t)num_node_blocks * 4 + 15) / 16) * 16;
    size_t entries_bytes = (size_t)n_edges * 8;

    size_t needed = 2 * node_buf + off_bytes + cur_bytes + bsum_bytes + entries_bytes;

    float* bufA = (float*)d_ws;
    float* bufB = (float*)((char*)d_ws + node_buf);

    int edge_blocks = (n_edges + 255) / 256;
    int agg_blocks = (N_NODES * HID + 255) / 256;  // 16 lanes per node

    if (ws_size >= needed) {
        char* p = (char*)d_ws + 2 * node_buf;
        int* offsets   = (int*)p;            p += off_bytes;
        int* cursor    = (int*)p;            p += cur_bytes;   // also deg
        int* blockSums = (int*)p;            p += bsum_bytes;
        int2* entries  = (int2*)p;

        // h1 = x @ W1
        gemm1_kernel<<<num_node_blocks, 256, 0, stream>>>(x, W1, bufA);

        // CSR build (overlaps gemm1 only through stream order; all on stream)
        hipMemsetAsync(cursor, 0, cur_bytes, stream);
        count_kernel<<<edge_blocks, 256, 0, stream>>>(edst, cursor, n_edges);
        scan1_kernel<<<num_node_blocks, 256, 0, stream>>>(cursor, offsets, blockSums);
        scan2_kernel<<<1, 1024, 0, stream>>>(blockSums, num_node_blocks);
        scan3_kernel<<<num_node_blocks, 256, 0, stream>>>(offsets, cursor, blockSums, n_edges);
        fill_kernel<<<edge_blocks, 256, 0, stream>>>(esrc, edst, ew, cursor, entries, n_edges);

        // layer-1 aggregate + bias/relu + W2  -> bufB
        agg_mid_kernel<<<agg_blocks, 256, 0, stream>>>(bufA, offsets, entries, b1, W2, bufB);
        // layer-2 aggregate + bias/relu + Wd  -> out
        agg_final_kernel<<<agg_blocks, 256, 0, stream>>>(bufB, offsets, entries, b2, Wd, bd, out);
    } else {
        // Fallback: R1 atomic path (needs only 2 node buffers)
        long long scatter_work = (long long)n_edges * HID;
        int scatter_blocks = (int)((scatter_work + 255) / 256);
        gemm1_kernel<<<num_node_blocks, 256, 0, stream>>>(x, W1, bufA);
        hipMemsetAsync(bufB, 0, node_buf, stream);
        scatter_kernel<<<scatter_blocks, 256, 0, stream>>>(bufA, esrc, edst, ew, bufB, n_edges);
        gemm2_kernel<<<num_node_blocks, 256, 0, stream>>>(bufB, b1, W2, bufA);
        hipMemsetAsync(bufB, 0, node_buf, stream);
        scatter_kernel<<<scatter_blocks, 256, 0, stream>>>(bufA, esrc, edst, ew, bufB, n_edges);
        final_kernel<<<num_node_blocks, 256, 0, stream>>>(bufB, b2, Wd, bd, out);
    }
}